// Round 1
// baseline (762.341 us; speedup 1.0000x reference)
//
#include <hip/hip_runtime.h>
#include <hip/hip_fp16.h>

#define NN 8192
#define FF 128
#define HH 64
#define GG 4
#define CONV_TH2 1e-10f

typedef _Float16 half8 __attribute__((ext_vector_type(8)));
typedef float floatx4 __attribute__((ext_vector_type(4)));

// ws layout (bytes)
#define OFF_WIU  134217728ull                  // Lh: [8192][8192] fp16 = 128 MB
#define OFF_LIN  142606336ull                  // wiu: [8192][256] fp32 = 8 MB
#define OFF_CP   146800640ull                  // lin_t: [256][8192] fp16 = 4 MB
#define OFF_META 180355072ull                  // C_part: [4][8192][256] fp32 = 32 MB

__device__ __forceinline__ void load16(const void* g, void* l) {
  __builtin_amdgcn_global_load_lds((const __attribute__((address_space(1))) void*)g,
                                   (__attribute__((address_space(3))) void*)l,
                                   16, 0, 0);
}

__global__ void k_init(float* __restrict__ diffsq, int* __restrict__ done) {
  int t = threadIdx.x;
  if (t < 5 * GG) diffsq[t] = 0.f;
  if (t < GG) done[t] = 0;
}

__global__ void k_done(const float* __restrict__ diffsq, int* __restrict__ done, int it) {
  int t = threadIdx.x;
  if (t < GG) {
    if (diffsq[it * GG + t] < CONV_TH2) done[t] = 1;
  }
}

__global__ __launch_bounds__(256) void k_convert(const float* __restrict__ L,
                                                 _Float16* __restrict__ Lh) {
  size_t i = ((size_t)blockIdx.x * 256 + threadIdx.x) * 8;
  float4 a = *(const float4*)(L + i);
  float4 b = *(const float4*)(L + i + 4);
  half8 h;
  h[0] = (_Float16)a.x; h[1] = (_Float16)a.y; h[2] = (_Float16)a.z; h[3] = (_Float16)a.w;
  h[4] = (_Float16)b.x; h[5] = (_Float16)b.y; h[6] = (_Float16)b.z; h[7] = (_Float16)b.w;
  *(half8*)(Lh + i) = h;
}

// wiu = X @ W_ih[g]^T ; hx1 = tanh(wiu) ; diff1 = ||hx1||^2 ; lin_t for iter 2
__global__ __launch_bounds__(256) void k_wiu(const float* __restrict__ X,
    const float* __restrict__ Wih, const float* __restrict__ Whh,
    float* __restrict__ wiu, float* __restrict__ hx,
    _Float16* __restrict__ lin_t, float* __restrict__ diffsq) {
  __shared__ __align__(16) float smem[2 * 64 * 128];   // 64 KB
  float* Xs = smem;              // [64][128], XOR-swizzled float4 chunks
  float* Ws = smem + 64 * 128;
  const int bx = blockIdx.x, g = blockIdx.y;
  const int t = threadIdx.x;
  const int m0 = bx * 64;
  #pragma unroll
  for (int p = 0; p < 8; ++p) {
    int idx = p * 256 + t;       // float4 id 0..2047
    int row = idx >> 5;
    int c4 = idx & 31;
    int sw = (c4 ^ (row >> 2)) & 31;
    float4 xv = *(const float4*)(X + (size_t)(m0 + row) * FF + c4 * 4);
    *(float4*)(Xs + row * 128 + sw * 4) = xv;
    float4 wv = *(const float4*)(Wih + (size_t)g * HH * FF + (size_t)row * FF + c4 * 4);
    *(float4*)(Ws + row * 128 + sw * 4) = wv;
  }
  __syncthreads();
  const int tc = t & 15, tm = t >> 4;
  float acc[4][4];
  #pragma unroll
  for (int r = 0; r < 4; ++r)
    #pragma unroll
    for (int s = 0; s < 4; ++s) acc[r][s] = 0.f;
  for (int f4 = 0; f4 < 32; ++f4) {
    float4 xv[4], wv[4];
    #pragma unroll
    for (int r = 0; r < 4; ++r) {
      int m = tm * 4 + r;
      xv[r] = *(const float4*)(Xs + m * 128 + (((f4 ^ (m >> 2)) & 31) * 4));
    }
    #pragma unroll
    for (int s = 0; s < 4; ++s) {
      int c = tc * 4 + s;
      wv[s] = *(const float4*)(Ws + c * 128 + (((f4 ^ (c >> 2)) & 31) * 4));
    }
    #pragma unroll
    for (int r = 0; r < 4; ++r)
      #pragma unroll
      for (int s = 0; s < 4; ++s)
        acc[r][s] += xv[r].x * wv[s].x + xv[r].y * wv[s].y +
                     xv[r].z * wv[s].z + xv[r].w * wv[s].w;
  }
  __syncthreads();               // done with Xs/Ws; alias below
  float* hxs = smem;             // [64][65]
  float* Whs = smem + 64 * 65;   // [64][65]
  float diffp = 0.f;
  #pragma unroll
  for (int r = 0; r < 4; ++r) {
    int ml = tm * 4 + r;
    size_t off = (size_t)(m0 + ml) * 256 + g * 64 + tc * 4;
    float4 wv = make_float4(acc[r][0], acc[r][1], acc[r][2], acc[r][3]);
    *(float4*)(wiu + off) = wv;
    float4 hv;
    hv.x = tanhf(wv.x); hv.y = tanhf(wv.y); hv.z = tanhf(wv.z); hv.w = tanhf(wv.w);
    *(float4*)(hx + off) = hv;
    hxs[ml * 65 + tc * 4 + 0] = hv.x;
    hxs[ml * 65 + tc * 4 + 1] = hv.y;
    hxs[ml * 65 + tc * 4 + 2] = hv.z;
    hxs[ml * 65 + tc * 4 + 3] = hv.w;
    diffp += hv.x * hv.x + hv.y * hv.y + hv.z * hv.z + hv.w * hv.w;
  }
  #pragma unroll
  for (int p = 0; p < 16; ++p) {
    int idx = p * 256 + t;
    Whs[(idx >> 6) * 65 + (idx & 63)] = Whh[(size_t)g * HH * HH + idx];
  }
  for (int o = 32; o; o >>= 1) diffp += __shfl_down(diffp, o);
  if ((t & 63) == 0) atomicAdd(diffsq + g, diffp);
  __syncthreads();
  const int ml = t & 63, wv_ = t >> 6;
  float lacc[16];
  #pragma unroll
  for (int i = 0; i < 16; ++i) lacc[i] = 0.f;
  for (int h = 0; h < 64; ++h) {
    float xh = hxs[ml * 65 + h];
    #pragma unroll
    for (int i = 0; i < 16; ++i)
      lacc[i] += xh * Whs[(wv_ + 4 * i) * 65 + h];
  }
  #pragma unroll
  for (int i = 0; i < 16; ++i)
    lin_t[(size_t)(g * 64 + wv_ + 4 * i) * NN + m0 + ml] = (_Float16)lacc[i];
}

// C_part[bz] = Lh[m0:m0+128, k0:k0+2048] @ lin_t^T[., c0:c0+128]
__global__ __launch_bounds__(256) void k_gemm(const _Float16* __restrict__ A,
    const _Float16* __restrict__ Bt, float* __restrict__ Cp) {
  __shared__ __align__(16) _Float16 As[128 * 64];  // [row m][64 k], chunk-swizzled
  __shared__ __align__(16) _Float16 Bs[128 * 64];  // [row n][64 k], chunk-swizzled
  const int bx = blockIdx.x;   // m block (128 rows)
  const int by = blockIdx.y;   // n block (128 cols)
  const int bz = blockIdx.z;   // k chunk (2048)
  const int t = threadIdx.x;
  const int lane = t & 63, wid = t >> 6;
  const int wr = wid >> 1, wc = wid & 1;
  const int l15 = lane & 15, quad = lane >> 4;
  const size_t m0 = (size_t)bx * 128;
  const size_t c0 = (size_t)by * 128;
  const size_t k0 = (size_t)bz * 2048;

  // staging sources/dests (chunk ch holds global k-chunk j = (ch&7)^(r&7))
  const _Float16* ga[4]; const _Float16* gb[4];
  _Float16* la[4]; _Float16* lb[4];
  #pragma unroll
  for (int i = 0; i < 4; ++i) {
    int ch = i * 256 + t;
    int r = ch >> 3;
    int j = (ch & 7) ^ (r & 7);
    ga[i] = A + (m0 + r) * NN + k0 + j * 8;
    gb[i] = Bt + (c0 + r) * NN + k0 + j * 8;
    la[i] = &As[ch * 8];
    lb[i] = &Bs[ch * 8];
  }
  // fragment LDS offsets (in halfs), constant across rounds
  int aoffs[2][4], boffs[2][4];
  #pragma unroll
  for (int ks = 0; ks < 2; ++ks) {
    #pragma unroll
    for (int mt = 0; mt < 4; ++mt) {
      int m = wr * 64 + mt * 16 + l15;
      aoffs[ks][mt] = m * 64 + (((ks * 4 + quad) ^ (m & 7)) * 8);
    }
    #pragma unroll
    for (int nt = 0; nt < 4; ++nt) {
      int n = wc * 64 + nt * 16 + l15;
      boffs[ks][nt] = n * 64 + (((ks * 4 + quad) ^ (n & 7)) * 8);
    }
  }
  floatx4 acc[4][4];
  #pragma unroll
  for (int mt = 0; mt < 4; ++mt)
    #pragma unroll
    for (int nt = 0; nt < 4; ++nt)
      acc[mt][nt] = (floatx4){0.f, 0.f, 0.f, 0.f};

  for (int rd = 0; rd < 32; ++rd) {
    #pragma unroll
    for (int i = 0; i < 4; ++i) { load16(ga[i], la[i]); load16(gb[i], lb[i]); }
    __syncthreads();
    #pragma unroll
    for (int ks = 0; ks < 2; ++ks) {
      half8 af[4], bf[4];
      #pragma unroll
      for (int mt = 0; mt < 4; ++mt) af[mt] = *(const half8*)&As[aoffs[ks][mt]];
      #pragma unroll
      for (int nt = 0; nt < 4; ++nt) bf[nt] = *(const half8*)&Bs[boffs[ks][nt]];
      #pragma unroll
      for (int mt = 0; mt < 4; ++mt)
        #pragma unroll
        for (int nt = 0; nt < 4; ++nt)
          acc[mt][nt] = __builtin_amdgcn_mfma_f32_16x16x32_f16(af[mt], bf[nt], acc[mt][nt], 0, 0, 0);
    }
    __syncthreads();
    #pragma unroll
    for (int i = 0; i < 4; ++i) { ga[i] += 64; gb[i] += 64; }
  }
  // write partial C: C/D layout col=lane&15, row=quad*4+reg
  float* Cb = Cp + (size_t)bz * NN * 256;
  #pragma unroll
  for (int mt = 0; mt < 4; ++mt) {
    #pragma unroll
    for (int nt = 0; nt < 4; ++nt) {
      size_t gm = m0 + wr * 64 + mt * 16 + quad * 4;
      size_t gc = c0 + wc * 64 + nt * 16 + l15;
      #pragma unroll
      for (int rg = 0; rg < 4; ++rg)
        Cb[(gm + rg) * 256 + gc] = acc[mt][nt][rg];
    }
  }
}

// sum split-K partials, new=tanh(wiu+C), mask with done_prev, diff^2, lin for next iter
__global__ __launch_bounds__(256) void k_post(const float* __restrict__ Cp,
    const float* __restrict__ wiu, const float* __restrict__ Whh,
    float* __restrict__ hx, _Float16* __restrict__ lin_t,
    float* __restrict__ diffsq, const int* __restrict__ done,
    int it, int write_lin) {
  __shared__ float hxs[64 * 65];
  __shared__ float Whs[64 * 65];
  const int bx = blockIdx.x, g = blockIdx.y, t = threadIdx.x;
  const int m0 = bx * 64;
  const int tcol = t & 15, trow = t >> 4;
  const int dn = done[g];
  float diffp = 0.f;
  #pragma unroll
  for (int p = 0; p < 4; ++p) {
    int ml = p * 16 + trow;
    size_t off = (size_t)(m0 + ml) * 256 + g * 64 + tcol * 4;
    float4 s  = *(const float4*)(Cp + off);
    float4 q1 = *(const float4*)(Cp + (size_t)1 * NN * 256 + off);
    float4 q2 = *(const float4*)(Cp + (size_t)2 * NN * 256 + off);
    float4 q3 = *(const float4*)(Cp + (size_t)3 * NN * 256 + off);
    s.x += q1.x + q2.x + q3.x; s.y += q1.y + q2.y + q3.y;
    s.z += q1.z + q2.z + q3.z; s.w += q1.w + q2.w + q3.w;
    float4 wv = *(const float4*)(wiu + off);
    float4 old = *(const float4*)(hx + off);
    float4 nv;
    nv.x = tanhf(wv.x + s.x); nv.y = tanhf(wv.y + s.y);
    nv.z = tanhf(wv.z + s.z); nv.w = tanhf(wv.w + s.w);
    float4 ov;
    ov.x = dn ? old.x : nv.x; ov.y = dn ? old.y : nv.y;
    ov.z = dn ? old.z : nv.z; ov.w = dn ? old.w : nv.w;
    *(float4*)(hx + off) = ov;
    float dx = nv.x - old.x, dy = nv.y - old.y, dz = nv.z - old.z, dw = nv.w - old.w;
    diffp += dx * dx + dy * dy + dz * dz + dw * dw;
    hxs[ml * 65 + tcol * 4 + 0] = ov.x;
    hxs[ml * 65 + tcol * 4 + 1] = ov.y;
    hxs[ml * 65 + tcol * 4 + 2] = ov.z;
    hxs[ml * 65 + tcol * 4 + 3] = ov.w;
  }
  if (write_lin) {
    #pragma unroll
    for (int p = 0; p < 16; ++p) {
      int idx = p * 256 + t;
      Whs[(idx >> 6) * 65 + (idx & 63)] = Whh[(size_t)g * HH * HH + idx];
    }
  }
  for (int o = 32; o; o >>= 1) diffp += __shfl_down(diffp, o);
  if ((t & 63) == 0) atomicAdd(diffsq + it * GG + g, diffp);
  if (!write_lin) return;
  __syncthreads();
  const int ml = t & 63, wv_ = t >> 6;
  float lacc[16];
  #pragma unroll
  for (int i = 0; i < 16; ++i) lacc[i] = 0.f;
  for (int h = 0; h < 64; ++h) {
    float xh = hxs[ml * 65 + h];
    #pragma unroll
    for (int i = 0; i < 16; ++i)
      lacc[i] += xh * Whs[(wv_ + 4 * i) * 65 + h];
  }
  #pragma unroll
  for (int i = 0; i < 16; ++i)
    lin_t[(size_t)(g * 64 + wv_ + 4 * i) * NN + m0 + ml] = (_Float16)lacc[i];
}

extern "C" void kernel_launch(void* const* d_in, const int* in_sizes, int n_in,
                              void* d_out, int out_size, void* d_ws, size_t ws_size,
                              hipStream_t stream) {
  const float* X   = (const float*)d_in[0];
  const float* L   = (const float*)d_in[1];
  const float* Wih = (const float*)d_in[2];
  const float* Whh = (const float*)d_in[3];
  float* out = (float*)d_out;
  char* ws = (char*)d_ws;
  _Float16* Lh    = (_Float16*)ws;
  float*    wiu   = (float*)(ws + OFF_WIU);
  _Float16* lin_t = (_Float16*)(ws + OFF_LIN);
  float*    Cp    = (float*)(ws + OFF_CP);
  float*    diffsq = (float*)(ws + OFF_META);
  int*      done   = (int*)(ws + OFF_META + 128);

  k_init<<<1, 64, 0, stream>>>(diffsq, done);
  k_convert<<<32768, 256, 0, stream>>>(L, Lh);
  k_wiu<<<dim3(128, 4), 256, 0, stream>>>(X, Wih, Whh, wiu, out, lin_t, diffsq);
  k_done<<<1, 64, 0, stream>>>(diffsq, done, 0);
  for (int it = 1; it <= 4; ++it) {
    k_gemm<<<dim3(64, 2, 4), 256, 0, stream>>>(Lh, lin_t, Cp);
    k_post<<<dim3(128, 4), 256, 0, stream>>>(Cp, wiu, Whh, out, lin_t, diffsq, done,
                                             it, (it < 4) ? 1 : 0);
    k_done<<<1, 64, 0, stream>>>(diffsq, done, it);
  }
}